// Round 9
// baseline (513.803 us; speedup 1.0000x reference)
//
#include <hip/hip_runtime.h>
#include <float.h>

// Viterbi decode: B=1024, T=1024, K=48.
// R9: FUSED fwd+bwd, 512 blocks x 128 threads (2 waves = 2 sequences/block).
//   Phase 1 (fwd, R4-proven body per wave): LDS b128 same-address broadcast
//     of fv, exec-masked to 48 lanes, 8-row double-buffered feat prefetch,
//     tr pinned. DS geometry per CU unchanged (4 waves x 13 ops) -> 218us.
//   __syncthreads: implicit vmcnt(0) drains both waves' mx stores; terminal
//     tags exchanged via LDS.
//   Phase 2 (bwd): wave 1 exits; wave 0 runs TWO equality-vote chains in
//     lockstep (seq A + seq B). The per-step ~120cyc tl[tag*48+rl] LDS read
//     latencies of the two chains overlap (chain latency, not issue, is the
//     bwd bound: 211cyc/step at ~25cyc issue). Lean: 2x32 buffer VGPRs,
//     statically named (R7's 4-chain failed at 128 buffer regs).
//   Bit-exact per-chain logic (vote: s = F + tr_row == mx_j[tag] ->
//     ballot -> ctz = np.argmax first-tie).
// FALLBACK (ws too small for mx): bptr pipeline, unchanged.

#define BB 1024
#define TT 1024
#define KK 48
#define CC 16
#define LL 64
#define NEGV -10000.0f

__device__ __forceinline__ float rdlane(float v, int l) {
  return __int_as_float(__builtin_amdgcn_readlane(__float_as_int(v), l));
}
__device__ __forceinline__ float max3f(float a, float b, float c) {
  return fmaxf(fmaxf(a, b), c);
}

// ---------------- main path: fused fwd + dual-chain bwd ----------------

#define FSTEP(T_, FEAT_)                                                   \
  {                                                                        \
    float fvr[KK];                                                         \
    _Pragma("unroll") for (int j = 0; j < 12; ++j) {                       \
      float4 v4 = *(const float4*)(&fvb[4 * j]);                           \
      fvr[4 * j + 0] = v4.x; fvr[4 * j + 1] = v4.y;                        \
      fvr[4 * j + 2] = v4.z; fvr[4 * j + 3] = v4.w;                        \
    }                                                                      \
    float s_[KK];                                                          \
    _Pragma("unroll") for (int p = 0; p < KK; ++p) {                       \
      s_[p] = fvr[p] + tr[p];                                              \
    }                                                                      \
    float part[16];                                                        \
    _Pragma("unroll") for (int g = 0; g < 16; ++g) {                       \
      part[g] = max3f(s_[3 * g], s_[3 * g + 1], s_[3 * g + 2]);            \
    }                                                                      \
    float q0 = max3f(part[0], part[1], part[2]);                           \
    float q1 = max3f(part[3], part[4], part[5]);                           \
    float q2 = max3f(part[6], part[7], part[8]);                           \
    float q3 = max3f(part[9], part[10], part[11]);                         \
    float q4 = max3f(part[12], part[13], part[14]);                        \
    float m_ = fmaxf(max3f(q0, q1, q2), max3f(q3, q4, part[15]));          \
    mp[(size_t)(T_)*KK] = m_;                                              \
    fv = m_ + (FEAT_);                                                     \
    __builtin_amdgcn_wave_barrier();                                       \
    fvb[lane] = fv;                                                        \
    __builtin_amdgcn_wave_barrier();                                       \
  }

__global__ __launch_bounds__(128, 1) void viterbi_fused2(
    const float* __restrict__ feats, const float* __restrict__ trans,
    float* __restrict__ scores, float* __restrict__ mx,
    float* __restrict__ path) {
  __shared__ __align__(16) float fvbuf[2][64];
  __shared__ float tl[KK * KK];
  __shared__ int tagsh[2];
  const int tid = threadIdx.x;
  const int w = tid >> 6;       // wave id -> sequence 2*bx + w
  const int lane = tid & 63;
  const int rl = (lane < KK) ? lane : (KK - 1);
  const int bA = blockIdx.x * 2;
  const int b = bA + w;
  float* fvb = &fvbuf[w][0];

  float tr[KK];
#pragma unroll
  for (int j = 0; j < 12; ++j) {
    float4 t4 = *(const float4*)(trans + rl * KK + 4 * j);
    tr[4 * j + 0] = t4.x; tr[4 * j + 1] = t4.y;
    tr[4 * j + 2] = t4.z; tr[4 * j + 3] = t4.w;
  }
#pragma unroll
  for (int j = 0; j < KK; ++j) asm volatile("" : "+v"(tr[j]));
  const float tstop = trans[(KK - 1) * KK + rl];
  for (int i = tid; i < KK * KK; i += 128) tl[i] = trans[i];

  const float* fp = feats + (size_t)b * TT * KK + rl;
  float* mp = mx + (size_t)b * TT * KK + rl;

  float fv = (lane == 46) ? 0.0f : NEGV;  // F_0
  fvb[lane] = fv;
  __builtin_amdgcn_wave_barrier();

  // ---------------- phase 1: forward (per wave, R4-proven) ----------------
  if (lane < KK) {
    float fA[8], fB[8];
#pragma unroll
    for (int k = 0; k < 8; ++k) fA[k] = fp[(size_t)k * KK];

    for (int t0 = 0; t0 < TT; t0 += 16) {
#pragma unroll
      for (int k = 0; k < 8; ++k)
        fB[k] = fp[(size_t)((t0 + 8 + k) & (TT - 1)) * KK];
#pragma unroll
      for (int u = 0; u < 8; ++u) FSTEP(t0 + u, fA[u]);
#pragma unroll
      for (int k = 0; k < 8; ++k)
        fA[k] = fp[(size_t)((t0 + 16 + k) & (TT - 1)) * KK];
#pragma unroll
      for (int u = 0; u < 8; ++u) FSTEP(t0 + 8 + u, fB[u]);
    }
  }

  // terminal argmax per wave (uniform in wave)
  float v = (lane < KK) ? (fv + tstop) : -FLT_MAX;
  int idx = lane;
#pragma unroll
  for (int off = 32; off >= 1; off >>= 1) {
    float ov = __shfl_xor(v, off);
    int oi = __shfl_xor(idx, off);
    bool take = (ov > v) || (ov == v && oi < idx);
    v = take ? ov : v;
    idx = take ? oi : idx;
  }
  if (lane == 0) { scores[b] = v; tagsh[w] = idx; }

  // barrier: implicit vmcnt(0) drains both waves' mx stores (same CU ->
  // L1/L2 coherent for wave 0's readback); tagsh visible.
  __syncthreads();
  if (w == 1) return;  // no barriers below

  // ---------------- phase 2: dual-chain backtrack (wave 0) ----------------
  int tagA = tagsh[0], tagB = tagsh[1];
  const float* fpA = fp;                                    // seq A (= b=bA)
  const float* mpA = mp;
  const float* fpB = feats + (size_t)(bA + 1) * TT * KK + rl;
  const float* mpB = mx + (size_t)(bA + 1) * TT * KK + rl;
  float* pathA = path + (size_t)bA * TT;
  float* pathB = path + (size_t)(bA + 1) * TT;

  float topA_A = mpA[(size_t)(TT - 1) * KK];
  float topA_B = mpB[(size_t)(TT - 1) * KK];
  float MAa[8], FEa[8], MBa[8], FBa[8];
  float MAb[8], FEb[8], MBb[8], FBb[8];
#pragma unroll
  for (int u = 0; u < 8; ++u) {
    MAa[u] = mpA[(size_t)(TT - 2 - u) * KK];
    FEa[u] = fpA[(size_t)(TT - 2 - u) * KK];
    MAb[u] = mpB[(size_t)(TT - 2 - u) * KK];
    FEb[u] = fpB[(size_t)(TT - 2 - u) * KK];
  }

  int myvA = 0, myvB = 0;  // lane (j&63) holds path[j] per chain
  for (int jb = TT - 1; jb >= 15; jb -= 16) {
    // bulk load block jb-8 (rows jb-9-u), clamped, both chains
#pragma unroll
    for (int u = 0; u < 8; ++u) {
      int r = jb - 9 - u; int rc = r < 0 ? 0 : r;
      MBa[u] = mpA[(size_t)rc * KK];
      FBa[u] = fpA[(size_t)rc * KK];
      MBb[u] = mpB[(size_t)rc * KK];
      FBb[u] = fpB[(size_t)rc * KK];
    }
    // process block jb
#pragma unroll
    for (int u = 0; u < 8; ++u) {
      const int j = jb - u;
      if (lane == (j & 63)) { myvA = tagA; myvB = tagB; }
      if ((j & 63) == 0) {
        pathA[j + lane] = (float)myvA;
        pathB[j + lane] = (float)myvB;
      }
      // issue both chains' tl reads back-to-back: latencies overlap
      float tlA = tl[tagA * KK + rl];
      float tlB = tl[tagB * KK + rl];
      float TgA = (u == 0) ? topA_A : MAa[u - 1];
      float TgB = (u == 0) ? topA_B : MAb[u - 1];
      float tgtA = rdlane(TgA, tagA);
      float tgtB = rdlane(TgB, tagB);
      float sA = (MAa[u] + FEa[u]) + tlA;
      float sB = (MAb[u] + FEb[u]) + tlB;
      unsigned long long balA = __ballot(sA == tgtA);
      unsigned long long balB = __ballot(sB == tgtB);
      tagA = (int)__builtin_ctzll(balA);
      tagB = (int)__builtin_ctzll(balB);
    }
    float topB_A = MAa[7];
    float topB_B = MAb[7];
    // bulk load block jb-16 (rows jb-17-u), clamped
#pragma unroll
    for (int u = 0; u < 8; ++u) {
      int r = jb - 17 - u; int rc = r < 0 ? 0 : r;
      MAa[u] = mpA[(size_t)rc * KK];
      FEa[u] = fpA[(size_t)rc * KK];
      MAb[u] = mpB[(size_t)rc * KK];
      FEb[u] = fpB[(size_t)rc * KK];
    }
    // process block jb-8
#pragma unroll
    for (int u = 0; u < 8; ++u) {
      const int j = jb - 8 - u;
      if (lane == (j & 63)) { myvA = tagA; myvB = tagB; }
      if ((j & 63) == 0) {
        pathA[j + lane] = (float)myvA;
        pathB[j + lane] = (float)myvB;
      }
      float tlA = tl[tagA * KK + rl];
      float tlB = tl[tagB * KK + rl];
      float TgA = (u == 0) ? topB_A : MBa[u - 1];
      float TgB = (u == 0) ? topB_B : MBb[u - 1];
      float tgtA = rdlane(TgA, tagA);
      float tgtB = rdlane(TgB, tagB);
      float sA = (MBa[u] + FBa[u]) + tlA;
      float sB = (MBb[u] + FBb[u]) + tlB;
      unsigned long long balA = __ballot(sA == tgtA);
      unsigned long long balB = __ballot(sB == tgtB);
      tagA = (int)__builtin_ctzll(balA);  // garbage after j==0 vote: unused
      tagB = (int)__builtin_ctzll(balB);
    }
    topA_A = MBa[7];
    topA_B = MBb[7];
  }
}

// ---------------- fallback path (bptr pipeline) ----------------

__global__ __launch_bounds__(64, 1) void viterbi_fwd_f(
    const float* __restrict__ feats, const float* __restrict__ trans,
    float* __restrict__ scores, unsigned char* __restrict__ bptr,
    int* __restrict__ bestArr) {
  __shared__ __align__(16) float fvbuf[64];
  const int lane = threadIdx.x;
  const int b = blockIdx.x;
  const int rl = (lane < KK) ? lane : (KK - 1);

  float tr[KK];
#pragma unroll
  for (int j = 0; j < 12; ++j) {
    float4 t4 = *(const float4*)(trans + rl * KK + 4 * j);
    tr[4 * j + 0] = t4.x; tr[4 * j + 1] = t4.y;
    tr[4 * j + 2] = t4.z; tr[4 * j + 3] = t4.w;
  }
  const float tstop = trans[(KK - 1) * KK + rl];

  if (lane < KK) fvbuf[lane] = (lane == 46) ? 0.0f : NEGV;
  __builtin_amdgcn_wave_barrier();

  const float* fp = feats + (size_t)b * TT * KK + rl;
  unsigned char* bp = bptr + (size_t)b * TT * KK + lane;

  float fbuf[4];
#pragma unroll
  for (int k = 0; k < 4; ++k) fbuf[k] = fp[(size_t)k * KK];

  float fv = NEGV;
  for (int t0 = 0; t0 < TT; t0 += 4) {
#pragma unroll
    for (int u = 0; u < 4; ++u) {
      const int t = t0 + u;
      float fvr[KK];
#pragma unroll
      for (int j = 0; j < 12; ++j) {
        float4 v4 = *(const float4*)(&fvbuf[4 * j]);
        fvr[4 * j + 0] = v4.x; fvr[4 * j + 1] = v4.y;
        fvr[4 * j + 2] = v4.z; fvr[4 * j + 3] = v4.w;
      }
      __builtin_amdgcn_wave_barrier();

      float bs0 = fvr[0] + tr[0], bs1 = fvr[12] + tr[12];
      float bs2 = fvr[24] + tr[24], bs3 = fvr[36] + tr[36];
      int bi0 = 0, bi1 = 12, bi2 = 24, bi3 = 36;
#pragma unroll
      for (int p = 1; p < 12; ++p) {
        float s0 = fvr[p] + tr[p];
        float s1 = fvr[12 + p] + tr[12 + p];
        float s2 = fvr[24 + p] + tr[24 + p];
        float s3 = fvr[36 + p] + tr[36 + p];
        if (s0 > bs0) { bs0 = s0; bi0 = p; }
        if (s1 > bs1) { bs1 = s1; bi1 = 12 + p; }
        if (s2 > bs2) { bs2 = s2; bi2 = 24 + p; }
        if (s3 > bs3) { bs3 = s3; bi3 = 36 + p; }
      }
      bool c1 = bs1 > bs0;
      float m01 = c1 ? bs1 : bs0; int i01 = c1 ? bi1 : bi0;
      bool c3 = bs3 > bs2;
      float m23 = c3 ? bs3 : bs2; int i23 = c3 ? bi3 : bi2;
      bool cf = m23 > m01;
      float m = cf ? m23 : m01; int bpi = cf ? i23 : i01;

      float nfv = m + fbuf[u];
      int tpre = t + 4; if (tpre >= TT) tpre = 0;
      fbuf[u] = fp[(size_t)tpre * KK];

      if (lane < KK) {
        bp[(size_t)t * KK] = (unsigned char)bpi;
        fvbuf[lane] = nfv;
        fv = nfv;
      }
      __builtin_amdgcn_wave_barrier();
    }
  }

  float v = (lane < KK) ? (fv + tstop) : -FLT_MAX;
  int idx = lane;
#pragma unroll
  for (int off = 32; off >= 1; off >>= 1) {
    float ov = __shfl_xor(v, off);
    int oi = __shfl_xor(idx, off);
    bool take = (ov > v) || (ov == v && oi < idx);
    v = take ? ov : v;
    idx = take ? oi : idx;
  }
  if (lane == 0) { scores[b] = v; bestArr[b] = idx; }
}

__global__ __launch_bounds__(256) void bwd_map(
    const unsigned char* __restrict__ bptr, unsigned char* __restrict__ cmap) {
  const int lane = threadIdx.x & 63;
  const int wg = blockIdx.x * 4 + (threadIdx.x >> 6);
  const int b = wg >> 4;
  const int c = wg & (CC - 1);
  const int rl = (lane < KK) ? lane : (KK - 1);
  const unsigned char* bp = bptr + ((size_t)b * TT + (size_t)c * LL) * KK + rl;

  int x = rl;
  const int CH = 16;
  int cur[CH], nxt[CH];
#pragma unroll
  for (int j = 0; j < CH; ++j) cur[j] = bp[(size_t)(LL - CH + j) * KK];
  for (int tb = LL - CH; tb >= 0; tb -= CH) {
    if (tb >= CH) {
#pragma unroll
      for (int j = 0; j < CH; ++j) nxt[j] = bp[(size_t)(tb - CH + j) * KK];
    }
#pragma unroll
    for (int j = CH - 1; j >= 0; --j) x = __shfl(cur[j], x);
    if (tb >= CH) {
#pragma unroll
      for (int j = 0; j < CH; ++j) cur[j] = nxt[j];
    }
  }
  if (lane < KK) cmap[(size_t)wg * KK + lane] = (unsigned char)x;
}

__global__ __launch_bounds__(256) void bwd_entry(
    const unsigned char* __restrict__ cmap, const int* __restrict__ bestArr,
    int* __restrict__ entry) {
  const int lane = threadIdx.x & 63;
  const int b = blockIdx.x * 4 + (threadIdx.x >> 6);
  const int rl = (lane < KK) ? lane : (KK - 1);

  int rows[CC];
#pragma unroll
  for (int c = 0; c < CC; ++c) rows[c] = cmap[((size_t)b * CC + c) * KK + rl];

  int tag = bestArr[b];
  int ev = 0;
#pragma unroll
  for (int c = CC - 1; c >= 0; --c) {
    if (lane == c) ev = tag;
    tag = __shfl(rows[c], tag);
  }
  if (lane < CC) entry[b * CC + lane] = ev;
}

__global__ __launch_bounds__(256) void bwd_emit(
    const unsigned char* __restrict__ bptr, const int* __restrict__ entry,
    float* __restrict__ path) {
  const int lane = threadIdx.x & 63;
  const int wg = blockIdx.x * 4 + (threadIdx.x >> 6);
  const int b = wg >> 4;
  const int c = wg & (CC - 1);
  const int rl = (lane < KK) ? lane : (KK - 1);
  const unsigned char* bp = bptr + ((size_t)b * TT + (size_t)c * LL) * KK + rl;

  int x = entry[b * CC + c];
  int myv = 0;
  const int CH = 16;
  int cur[CH], nxt[CH];
#pragma unroll
  for (int j = 0; j < CH; ++j) cur[j] = bp[(size_t)(LL - CH + j) * KK];
  for (int tb = LL - CH; tb >= 0; tb -= CH) {
    if (tb >= CH) {
#pragma unroll
      for (int j = 0; j < CH; ++j) nxt[j] = bp[(size_t)(tb - CH + j) * KK];
    }
#pragma unroll
    for (int j = CH - 1; j >= 0; --j) {
      if (lane == tb + j) myv = x;
      x = __shfl(cur[j], x);
    }
    if (tb >= CH) {
#pragma unroll
      for (int j = 0; j < CH; ++j) cur[j] = nxt[j];
    }
  }
  path[(size_t)b * TT + (size_t)c * LL + lane] = (float)myv;
}

extern "C" void kernel_launch(void* const* d_in, const int* in_sizes, int n_in,
                              void* d_out, int out_size, void* d_ws,
                              size_t ws_size, hipStream_t stream) {
  const float* feats = (const float*)d_in[0];
  const float* trans = (const float*)d_in[1];
  float* out = (float*)d_out;  // [0,1024): scores; then paths [B*T]

  const size_t MX_BYTES = (size_t)BB * TT * KK * sizeof(float);  // 201.3 MB
  if (ws_size >= MX_BYTES) {
    float* mx = (float*)d_ws;
    viterbi_fused2<<<dim3(BB / 2), dim3(128), 0, stream>>>(feats, trans, out,
                                                           mx, out + BB);
  } else {
    unsigned char* bptr = (unsigned char*)d_ws;
    char* p = (char*)d_ws + (size_t)BB * TT * KK;
    int* bestArr = (int*)p;
    p += BB * sizeof(int);
    unsigned char* cmap = (unsigned char*)p;
    p += (size_t)BB * CC * KK;
    int* entry = (int*)p;

    viterbi_fwd_f<<<dim3(BB), dim3(64), 0, stream>>>(feats, trans, out, bptr,
                                                     bestArr);
    bwd_map<<<dim3(BB * CC / 4), dim3(256), 0, stream>>>(bptr, cmap);
    bwd_entry<<<dim3(BB / 4), dim3(256), 0, stream>>>(cmap, bestArr, entry);
    bwd_emit<<<dim3(BB * CC / 4), dim3(256), 0, stream>>>(bptr, entry,
                                                          out + BB);
  }
}